// Round 6
// baseline (438.785 us; speedup 1.0000x reference)
//
#include <hip/hip_runtime.h>

// numpy rounds every op separately — keep contraction off everywhere.
#pragma clang fp contract(off)

#define N_PTS 8192
#define C_DIM 64
#define NQ (3 * N_PTS)          // 24576 queries
#define G 64                    // grid cells per axis
#define NCELL (G * G)           // 4096
#define RMAX 256
#define MARGIN 1.2e-5f          // covers 2*E(f32 expanded formula) + slack

// ws layout (ws >= 256MB per harness poison profile):
//   sorted  float4[8192]  @ 0        (131072 B)  (cx, cy, sc, idx-bits)
//   starts  int[4097]     @ 131072   (16388 B)
//   nn_idx  int[24576]    @ 147472   (98304 B)

// ---------------------------------------------------------------------------
// Kernel 1: single-block counting sort of the 8192 points into 64x64 cells.
// LDS histogram -> LDS Hillis-Steele scan -> scatter (LDS cursor atomics).
// sc = rn(rn(cx^2)+rn(cy^2)) stored to replicate reference bit-exactly.
// ---------------------------------------------------------------------------
__global__ __launch_bounds__(1024) void build_kernel(
    const float2* __restrict__ coords2,
    float4* __restrict__ sorted,
    int* __restrict__ starts)
{
#pragma clang fp contract(off)
    __shared__ unsigned int lhist[NCELL];   // 16 KB
    __shared__ unsigned int part[1024];     // 4 KB
    const int t = threadIdx.x;

    #pragma unroll
    for (int k = 0; k < 4; ++k) lhist[4 * t + k] = 0u;
    __syncthreads();

    #pragma unroll
    for (int k = 0; k < 8; ++k) {
        const int i = t + 1024 * k;
        const float2 c = coords2[i];
        int cx = (int)(c.x * 64.0f); cx = min(max(cx, 0), G - 1);
        int cy = (int)(c.y * 64.0f); cy = min(max(cy, 0), G - 1);
        atomicAdd(&lhist[cy * G + cx], 1u);
    }
    __syncthreads();

    const unsigned h0 = lhist[4 * t + 0], h1 = lhist[4 * t + 1];
    const unsigned h2 = lhist[4 * t + 2], h3 = lhist[4 * t + 3];
    part[t] = h0 + h1 + h2 + h3;
    __syncthreads();
    for (int s = 1; s < 1024; s <<= 1) {
        const unsigned v = (t >= s) ? part[t - s] : 0u;
        __syncthreads();
        part[t] += v;
        __syncthreads();
    }
    const unsigned e0 = (t == 0) ? 0u : part[t - 1];
    const unsigned e1 = e0 + h0, e2 = e1 + h1, e3 = e2 + h2;
    starts[4 * t + 0] = (int)e0; starts[4 * t + 1] = (int)e1;
    starts[4 * t + 2] = (int)e2; starts[4 * t + 3] = (int)e3;
    lhist[4 * t + 0] = e0; lhist[4 * t + 1] = e1;
    lhist[4 * t + 2] = e2; lhist[4 * t + 3] = e3;
    if (t == 0) starts[NCELL] = N_PTS;
    __syncthreads();

    #pragma unroll
    for (int k = 0; k < 8; ++k) {
        const int i = t + 1024 * k;
        const float2 c = coords2[i];
        int cx = (int)(c.x * 64.0f); cx = min(max(cx, 0), G - 1);
        int cy = (int)(c.y * 64.0f); cy = min(max(cy, 0), G - 1);
        const unsigned pos = atomicAdd(&lhist[cy * G + cx], 1u);
        const float p0 = c.x * c.x;            // contract off: separate rn ops
        const float p1 = c.y * c.y;
        const float sc = p0 + p1;
        sorted[pos] = make_float4(c.x, c.y, sc, __int_as_float(i));
    }
}

// ---------------------------------------------------------------------------
// Kernel 2: per-query expanding-ring NN search with the exact reference f32
// d2. Threads walk queries in sorted-point order (spatial coherence). Each
// query is owned by exactly one thread -> plain stores, replay-deterministic.
// Also writes out_coords rows [N, 4N) (it already has nx, ny).
// ---------------------------------------------------------------------------
__global__ __launch_bounds__(64) void query_kernel(
    const float4* __restrict__ sorted,
    const int* __restrict__ starts,
    const float* __restrict__ spacing,
    const float* __restrict__ shift,
    int* __restrict__ nn_idx,
    float2* __restrict__ out_coords)
{
#pragma clang fp contract(off)
    const int t = blockIdx.x * 64 + threadIdx.x;
    if (t >= NQ) return;
    const int g = t >> 13;          // query group 0..2
    const int k = t & (N_PTS - 1);  // sorted-order position

    const float4 me = sorted[k];
    const float x = me.x, y = me.y;
    const int b = __float_as_int(me.w);     // original point index

    const float sx = spacing[0], sy = spacing[1];
    const float sh0 = shift[0],  sh1 = shift[1];

    float nx, ny;
    if (g == 0)      { nx = x + sx; ny = y + sy; }
    else if (g == 1) { nx = x;      ny = y + sy; }
    else             { nx = x + sx; ny = y; }

    const float ax = nx - sh0;
    const float ay = ny - sh1;
    const float sa = (ax * ax) + (ay * ay);   // rn(rn+rn), no contraction

    const int qcx = (int)(ax * 64.0f);        // ax >= 0
    const int qcy = (int)(ay * 64.0f);

    float best = INFINITY;
    int   bidx = 0;
    const float hcell = 1.0f / 64.0f;

    // exact reference d2 + lex (d2, idx) update
#define EVAL_SPAN(S, E)                                                     \
    for (int i = (S); i < (E); ++i) {                                       \
        const float4 pt = sorted[i];                                        \
        const float p   = ax * pt.x;                                        \
        const float dv  = __builtin_fmaf(ay, pt.y, p);                      \
        const float t1  = sa + pt.z;                                        \
        const float d2  = t1 - (2.0f * dv);                                 \
        const int   j   = __float_as_int(pt.w);                             \
        if (d2 < best || (d2 == best && j < bidx)) { best = d2; bidx = j; } \
    }

    // jump-start past rings entirely off-grid (query may sit outside [0,1)^2)
    const int dxo = max(0, max(-qcx, qcx - (G - 1)));
    const int dyo = max(0, max(-qcy, qcy - (G - 1)));
    const int rs  = max(dxo, dyo);

    for (int r = rs; r < RMAX; ++r) {
        if (r > 0) {
            const float lb = (float)(r - 1) * hcell;
            if (lb * lb > best + MARGIN) break;
        }
        if (r == 0) {
            const int c0 = qcy * G + qcx;
            const int s = starts[c0], e = starts[c0 + 1];
            EVAL_SPAN(s, e)
        } else {
            const int x0 = qcx - r, x1 = qcx + r;
            const int y0 = qcy - r, y1 = qcy + r;
            const int xa = max(x0, 0), xb = min(x1, G - 1);
            if (xa <= xb) {
                if (y0 >= 0 && y0 < G) {       // top row: contiguous span
                    const int s = starts[y0 * G + xa], e = starts[y0 * G + xb + 1];
                    EVAL_SPAN(s, e)
                }
                if (y1 >= 0 && y1 < G) {       // bottom row
                    const int s = starts[y1 * G + xa], e = starts[y1 * G + xb + 1];
                    EVAL_SPAN(s, e)
                }
            }
            const int ya = max(y0 + 1, 0), yb = min(y1 - 1, G - 1);
            if (x0 >= 0 && x0 < G) {
                for (int yy = ya; yy <= yb; ++yy) {
                    const int c = yy * G + x0;
                    const int s = starts[c], e = starts[c + 1];
                    EVAL_SPAN(s, e)
                }
            }
            if (x1 >= 0 && x1 < G) {
                for (int yy = ya; yy <= yb; ++yy) {
                    const int c = yy * G + x1;
                    const int s = starts[c], e = starts[c + 1];
                    EVAL_SPAN(s, e)
                }
            }
        }
    }
#undef EVAL_SPAN

    const int qi = g * N_PTS + b;
    nn_idx[qi] = bidx;
    out_coords[N_PTS + qi] = make_float2(nx, ny);
}

// ---------------------------------------------------------------------------
// Kernel 3: out_values all 4N rows (copy + gather) and out_coords rows [0,N).
// 16 lanes per row, one float4 each.
// ---------------------------------------------------------------------------
__global__ __launch_bounds__(256) void gather_kernel(
    const float4* __restrict__ values4,
    const int* __restrict__ nn_idx,
    const float2* __restrict__ coords2,
    float4* __restrict__ out_values4,
    float2* __restrict__ out_coords)
{
    const int t   = blockIdx.x * 256 + threadIdx.x;
    const int row = t >> 4;
    const int c4  = t & 15;
    int src;
    if (row < N_PTS) {
        src = row;
        if (c4 == 0) out_coords[row] = coords2[row];
    } else {
        src = nn_idx[row - N_PTS];
    }
    out_values4[row * 16 + c4] = values4[src * 16 + c4];
}

extern "C" void kernel_launch(void* const* d_in, const int* in_sizes, int n_in,
                              void* d_out, int out_size, void* d_ws, size_t ws_size,
                              hipStream_t stream)
{
    const float* values  = (const float*)d_in[0];   // [8192,64]
    const float* coords  = (const float*)d_in[1];   // [8192,2]
    const float* spacing = (const float*)d_in[2];   // [2]
    const float* shift   = (const float*)d_in[3];   // [2]

    float* out_values = (float*)d_out;                          // [32768,64]
    float2* out_coords = (float2*)(out_values + (size_t)4 * N_PTS * C_DIM);

    char* ws = (char*)d_ws;
    float4* sorted = (float4*)ws;                   // 131072 B
    int* starts    = (int*)(ws + 131072);           // 16388 B
    int* nn_idx    = (int*)(ws + 147472);           // 98304 B

    build_kernel<<<1, 1024, 0, stream>>>((const float2*)coords, sorted, starts);

    query_kernel<<<NQ / 64, 64, 0, stream>>>(
        sorted, starts, spacing, shift, nn_idx, out_coords);

    gather_kernel<<<(4 * N_PTS * 16) / 256, 256, 0, stream>>>(
        (const float4*)values, nn_idx, (const float2*)coords,
        (float4*)out_values, out_coords);
}

// Round 7
// 334.606 us; speedup vs baseline: 1.3114x; 1.3114x over previous
//
#include <hip/hip_runtime.h>

// numpy rounds every op separately — keep contraction off everywhere.
#pragma clang fp contract(off)

#define N_PTS 8192
#define C_DIM 64
#define NQ (3 * N_PTS)          // 24576 queries
#define G 64                    // grid cells per axis
#define NCELL (G * G)           // 4096
#define MARGIN 1.2e-5f          // >> f32-formula + bound rounding error (~2.5e-6)
#define HCELL (1.0f / 64.0f)
#define H2CELL (HCELL * HCELL)

// ws layout:
//   sorted   float4[8192]  @ 0        (cx, cy, sc, idx-bits)
//   starts   int[4097]     @ 131072
//   nn_idx   int[24576]    @ 147472
//   ovfl_cnt int           @ 245776
//   ovfl     int[24576]    @ 245792

__device__ __forceinline__ unsigned int fsortkey(float f) {
    const unsigned int u = __float_as_uint(f);
    return (u & 0x80000000u) ? ~u : (u | 0x80000000u);
}
__device__ __forceinline__ float finvkey(unsigned int e) {
    const unsigned int u = (e & 0x80000000u) ? (e & 0x7fffffffu) : ~e;
    return __uint_as_float(u);
}

// shifted query from group g and base point (x,y) — reference f32 ops
__device__ __forceinline__ void shift_query(int g, float x, float y,
                                            float sx, float sy,
                                            float& nx, float& ny) {
    if (g == 0)      { nx = x + sx; ny = y + sy; }
    else if (g == 1) { nx = x;      ny = y + sy; }
    else             { nx = x + sx; ny = y; }
}

// ---------------------------------------------------------------------------
// Kernel 1: single-block counting sort into 64x64 cells (round-6, verified).
// ---------------------------------------------------------------------------
__global__ __launch_bounds__(1024) void build_kernel(
    const float2* __restrict__ coords2,
    float4* __restrict__ sorted,
    int* __restrict__ starts,
    int* __restrict__ ovfl_cnt)
{
#pragma clang fp contract(off)
    __shared__ unsigned int lhist[NCELL];   // 16 KB
    __shared__ unsigned int part[1024];     // 4 KB
    const int t = threadIdx.x;

    #pragma unroll
    for (int k = 0; k < 4; ++k) lhist[4 * t + k] = 0u;
    __syncthreads();

    #pragma unroll
    for (int k = 0; k < 8; ++k) {
        const int i = t + 1024 * k;
        const float2 c = coords2[i];
        int cx = (int)(c.x * 64.0f); cx = min(max(cx, 0), G - 1);
        int cy = (int)(c.y * 64.0f); cy = min(max(cy, 0), G - 1);
        atomicAdd(&lhist[cy * G + cx], 1u);
    }
    __syncthreads();

    const unsigned h0 = lhist[4 * t + 0], h1 = lhist[4 * t + 1];
    const unsigned h2 = lhist[4 * t + 2], h3 = lhist[4 * t + 3];
    part[t] = h0 + h1 + h2 + h3;
    __syncthreads();
    for (int s = 1; s < 1024; s <<= 1) {
        const unsigned v = (t >= s) ? part[t - s] : 0u;
        __syncthreads();
        part[t] += v;
        __syncthreads();
    }
    const unsigned e0 = (t == 0) ? 0u : part[t - 1];
    const unsigned e1 = e0 + h0, e2 = e1 + h1, e3 = e2 + h2;
    starts[4 * t + 0] = (int)e0; starts[4 * t + 1] = (int)e1;
    starts[4 * t + 2] = (int)e2; starts[4 * t + 3] = (int)e3;
    lhist[4 * t + 0] = e0; lhist[4 * t + 1] = e1;
    lhist[4 * t + 2] = e2; lhist[4 * t + 3] = e3;
    if (t == 0) { starts[NCELL] = N_PTS; ovfl_cnt[0] = 0; }
    __syncthreads();

    #pragma unroll
    for (int k = 0; k < 8; ++k) {
        const int i = t + 1024 * k;
        const float2 c = coords2[i];
        int cx = (int)(c.x * 64.0f); cx = min(max(cx, 0), G - 1);
        int cy = (int)(c.y * 64.0f); cy = min(max(cy, 0), G - 1);
        const unsigned pos = atomicAdd(&lhist[cy * G + cx], 1u);
        const float p0 = c.x * c.x;            // contract off: separate rn ops
        const float p1 = c.y * c.y;
        const float sc = p0 + p1;
        sorted[pos] = make_float4(c.x, c.y, sc, __int_as_float(i));
    }
}

// ---------------------------------------------------------------------------
// Kernel 2 (phase A): 8 lanes per query, fixed 3x3 neighborhood of the
// CLAMPED cell; lane-strided span evals; shfl lex-reduce; certify with
// lb = delta^2 + h^2. Uncertified queries -> overflow list for phase B.
// Exact reference f32 d2; lex (d2, idx) -> np.argmin semantics.
// ---------------------------------------------------------------------------
__global__ __launch_bounds__(256) void phaseA_kernel(
    const float4* __restrict__ sorted,
    const int* __restrict__ starts,
    const float* __restrict__ spacing,
    const float* __restrict__ shift,
    int* __restrict__ nn_idx,
    float2* __restrict__ out_coords,
    int* __restrict__ ovfl_cnt,
    int* __restrict__ ovfl)
{
#pragma clang fp contract(off)
    const int lane = threadIdx.x & 7;
    const int q    = blockIdx.x * 32 + (threadIdx.x >> 3);   // [0, NQ)
    const int g    = q >> 13;
    const int k    = q & (N_PTS - 1);

    const float4 me = sorted[k];
    const int b = __float_as_int(me.w);     // original point index

    float nx, ny;
    shift_query(g, me.x, me.y, spacing[0], spacing[1], nx, ny);
    const float ax = nx - shift[0];
    const float ay = ny - shift[1];
    const float sa = (ax * ax) + (ay * ay);

    int cx = (int)floorf(ax * 64.0f); cx = min(max(cx, 0), G - 1);
    int cy = (int)floorf(ay * 64.0f); cy = min(max(cy, 0), G - 1);
    const float dx = fmaxf(fmaxf(ax - 1.0f, -ax), 0.0f);
    const float dy = fmaxf(fmaxf(ay - 1.0f, -ay), 0.0f);
    const float dd = dx * dx + dy * dy;     // overhang^2 (our bound, any rounding)

    const int xa = max(cx - 1, 0), xb = min(cx + 1, G - 1);
    const int ya = max(cy - 1, 0), yb = min(cy + 1, G - 1);

    float best = INFINITY;
    int   bi   = 0x7fffffff;
    for (int yy = ya; yy <= yb; ++yy) {
        const int s = starts[yy * G + xa];
        const int e = starts[yy * G + xb + 1];
        for (int i = s + lane; i < e; i += 8) {
            const float4 pt = sorted[i];
            const float p   = ax * pt.x;
            const float dv  = __builtin_fmaf(ay, pt.y, p);
            const float t1  = sa + pt.z;
            const float d2  = t1 - (2.0f * dv);
            const int   j   = __float_as_int(pt.w);
            if (d2 < best || (d2 == best && j < bi)) { best = d2; bi = j; }
        }
    }

    unsigned long long key =
        ((unsigned long long)fsortkey(best) << 32) | (unsigned int)bi;
    #pragma unroll
    for (int m = 1; m < 8; m <<= 1) {
        const unsigned long long o = __shfl_xor(key, m, 8);
        if (o < key) key = o;
    }

    if (lane == 0) {
        const int qi = g * N_PTS + b;
        out_coords[N_PTS + qi] = make_float2(nx, ny);
        const float bf = finvkey((unsigned int)(key >> 32));
        const float lb = dd + H2CELL;       // unvisited cells >= 1 cell away
        if (lb > bf + MARGIN) {
            nn_idx[qi] = (int)(unsigned int)key;
        } else {
            const int p = atomicAdd(ovfl_cnt, 1);
            ovfl[p] = qi;
        }
    }
}

// ---------------------------------------------------------------------------
// Kernel 3 (phase B): serial expanding-ring walk from the clamped cell for
// the ~0.2% uncertified queries. lb = dd + ((r-1)h)^2.
// ---------------------------------------------------------------------------
__global__ __launch_bounds__(64) void phaseB_kernel(
    const float4* __restrict__ sorted,
    const int* __restrict__ starts,
    const float2* __restrict__ coords2,
    const float* __restrict__ spacing,
    const float* __restrict__ shift,
    const int* __restrict__ ovfl_cnt,
    const int* __restrict__ ovfl,
    int* __restrict__ nn_idx)
{
#pragma clang fp contract(off)
    const int n = ovfl_cnt[0];
    for (int o = blockIdx.x * 64 + threadIdx.x; o < n; o += gridDim.x * 64) {
        const int qi = ovfl[o];
        const int g  = qi >> 13;
        const int b  = qi & (N_PTS - 1);
        const float2 c = coords2[b];

        float nx, ny;
        shift_query(g, c.x, c.y, spacing[0], spacing[1], nx, ny);
        const float ax = nx - shift[0];
        const float ay = ny - shift[1];
        const float sa = (ax * ax) + (ay * ay);

        int cx = (int)floorf(ax * 64.0f); cx = min(max(cx, 0), G - 1);
        int cy = (int)floorf(ay * 64.0f); cy = min(max(cy, 0), G - 1);
        const float dx = fmaxf(fmaxf(ax - 1.0f, -ax), 0.0f);
        const float dy = fmaxf(fmaxf(ay - 1.0f, -ay), 0.0f);
        const float dd = dx * dx + dy * dy;

        float best = INFINITY;
        int   bi   = 0x7fffffff;

#define EVAL_SPAN(S, E)                                                       \
        for (int i = (S); i < (E); ++i) {                                     \
            const float4 pt = sorted[i];                                      \
            const float p   = ax * pt.x;                                      \
            const float dv  = __builtin_fmaf(ay, pt.y, p);                    \
            const float t1  = sa + pt.z;                                      \
            const float d2  = t1 - (2.0f * dv);                               \
            const int   j   = __float_as_int(pt.w);                           \
            if (d2 < best || (d2 == best && j < bi)) { best = d2; bi = j; }   \
        }

        for (int r = 0; r < G; ++r) {
            if (r > 0) {
                const float rr = (float)(r - 1) * HCELL;
                if (dd + rr * rr > best + MARGIN) break;
            }
            if (r == 0) {
                const int c0 = cy * G + cx;
                EVAL_SPAN(starts[c0], starts[c0 + 1])
            } else {
                const int x0 = cx - r, x1 = cx + r;
                const int y0 = cy - r, y1 = cy + r;
                const int xa2 = max(x0, 0), xb2 = min(x1, G - 1);
                if (xa2 <= xb2) {
                    if (y0 >= 0) {
                        const int s = starts[y0 * G + xa2];
                        const int e = starts[y0 * G + xb2 + 1];
                        EVAL_SPAN(s, e)
                    }
                    if (y1 < G) {
                        const int s = starts[y1 * G + xa2];
                        const int e = starts[y1 * G + xb2 + 1];
                        EVAL_SPAN(s, e)
                    }
                }
                const int ya2 = max(y0 + 1, 0), yb2 = min(y1 - 1, G - 1);
                if (x0 >= 0) {
                    for (int yy = ya2; yy <= yb2; ++yy) {
                        const int cc = yy * G + x0;
                        EVAL_SPAN(starts[cc], starts[cc + 1])
                    }
                }
                if (x1 < G) {
                    for (int yy = ya2; yy <= yb2; ++yy) {
                        const int cc = yy * G + x1;
                        EVAL_SPAN(starts[cc], starts[cc + 1])
                    }
                }
            }
        }
#undef EVAL_SPAN
        nn_idx[qi] = bi;
    }
}

// ---------------------------------------------------------------------------
// Kernel 4: out_values all 4N rows (copy + gather) and out_coords rows [0,N).
// ---------------------------------------------------------------------------
__global__ __launch_bounds__(256) void gather_kernel(
    const float4* __restrict__ values4,
    const int* __restrict__ nn_idx,
    const float2* __restrict__ coords2,
    float4* __restrict__ out_values4,
    float2* __restrict__ out_coords)
{
    const int t   = blockIdx.x * 256 + threadIdx.x;
    const int row = t >> 4;
    const int c4  = t & 15;
    int src;
    if (row < N_PTS) {
        src = row;
        if (c4 == 0) out_coords[row] = coords2[row];
    } else {
        src = nn_idx[row - N_PTS];
    }
    out_values4[row * 16 + c4] = values4[src * 16 + c4];
}

extern "C" void kernel_launch(void* const* d_in, const int* in_sizes, int n_in,
                              void* d_out, int out_size, void* d_ws, size_t ws_size,
                              hipStream_t stream)
{
    const float* values  = (const float*)d_in[0];   // [8192,64]
    const float* coords  = (const float*)d_in[1];   // [8192,2]
    const float* spacing = (const float*)d_in[2];   // [2]
    const float* shift   = (const float*)d_in[3];   // [2]

    float* out_values = (float*)d_out;                          // [32768,64]
    float2* out_coords = (float2*)(out_values + (size_t)4 * N_PTS * C_DIM);

    char* ws = (char*)d_ws;
    float4* sorted = (float4*)ws;                   // @0
    int* starts    = (int*)(ws + 131072);
    int* nn_idx    = (int*)(ws + 147472);
    int* ovfl_cnt  = (int*)(ws + 245776);
    int* ovfl      = (int*)(ws + 245792);

    build_kernel<<<1, 1024, 0, stream>>>(
        (const float2*)coords, sorted, starts, ovfl_cnt);

    phaseA_kernel<<<NQ / 32, 256, 0, stream>>>(
        sorted, starts, spacing, shift, nn_idx, out_coords, ovfl_cnt, ovfl);

    phaseB_kernel<<<64, 64, 0, stream>>>(
        sorted, starts, (const float2*)coords, spacing, shift,
        ovfl_cnt, ovfl, nn_idx);

    gather_kernel<<<(4 * N_PTS * 16) / 256, 256, 0, stream>>>(
        (const float4*)values, nn_idx, (const float2*)coords,
        (float4*)out_values, out_coords);
}

// Round 8
// 29.950 us; speedup vs baseline: 14.6506x; 11.1722x over previous
//
#include <hip/hip_runtime.h>

// numpy rounds every op separately — keep contraction off everywhere.
#pragma clang fp contract(off)

#define N_PTS 8192
#define C_DIM 64
#define NQ (3 * N_PTS)          // 24576 queries
#define G 64                    // grid cells per axis
#define NCELL (G * G)           // 4096
#define MARGIN 1.2e-5f          // >> 2*E(f32 formula ~3.5e-6) + binning/fp slop
#define HCELL (1.0f / 64.0f)

// ws layout:
//   sorted   float4[8192]  @ 0        (cx, cy, sc, idx-bits)
//   starts   int[4097]     @ 131072
//   nn_idx   int[24576]    @ 147472

__device__ __forceinline__ unsigned int fsortkey(float f) {
    const unsigned int u = __float_as_uint(f);
    return (u & 0x80000000u) ? ~u : (u | 0x80000000u);
}
__device__ __forceinline__ float finvkey(unsigned int e) {
    const unsigned int u = (e & 0x80000000u) ? (e & 0x7fffffffu) : ~e;
    return __uint_as_float(u);
}

// shifted query from group g and base point (x,y) — reference f32 ops
__device__ __forceinline__ void shift_query(int g, float x, float y,
                                            float sx, float sy,
                                            float& nx, float& ny) {
    if (g == 0)      { nx = x + sx; ny = y + sy; }
    else if (g == 1) { nx = x;      ny = y + sy; }
    else             { nx = x + sx; ny = y; }
}

// ---------------------------------------------------------------------------
// Kernel 1: single-block counting sort into 64x64 cells (verified r6/r7).
// ---------------------------------------------------------------------------
__global__ __launch_bounds__(1024) void build_kernel(
    const float2* __restrict__ coords2,
    float4* __restrict__ sorted,
    int* __restrict__ starts)
{
#pragma clang fp contract(off)
    __shared__ unsigned int lhist[NCELL];   // 16 KB
    __shared__ unsigned int part[1024];     // 4 KB
    const int t = threadIdx.x;

    #pragma unroll
    for (int k = 0; k < 4; ++k) lhist[4 * t + k] = 0u;
    __syncthreads();

    #pragma unroll
    for (int k = 0; k < 8; ++k) {
        const int i = t + 1024 * k;
        const float2 c = coords2[i];
        int cx = (int)(c.x * 64.0f); cx = min(max(cx, 0), G - 1);
        int cy = (int)(c.y * 64.0f); cy = min(max(cy, 0), G - 1);
        atomicAdd(&lhist[cy * G + cx], 1u);
    }
    __syncthreads();

    const unsigned h0 = lhist[4 * t + 0], h1 = lhist[4 * t + 1];
    const unsigned h2 = lhist[4 * t + 2], h3 = lhist[4 * t + 3];
    part[t] = h0 + h1 + h2 + h3;
    __syncthreads();
    for (int s = 1; s < 1024; s <<= 1) {
        const unsigned v = (t >= s) ? part[t - s] : 0u;
        __syncthreads();
        part[t] += v;
        __syncthreads();
    }
    const unsigned e0 = (t == 0) ? 0u : part[t - 1];
    const unsigned e1 = e0 + h0, e2 = e1 + h1, e3 = e2 + h2;
    starts[4 * t + 0] = (int)e0; starts[4 * t + 1] = (int)e1;
    starts[4 * t + 2] = (int)e2; starts[4 * t + 3] = (int)e3;
    lhist[4 * t + 0] = e0; lhist[4 * t + 1] = e1;
    lhist[4 * t + 2] = e2; lhist[4 * t + 3] = e3;
    if (t == 0) starts[NCELL] = N_PTS;
    __syncthreads();

    #pragma unroll
    for (int k = 0; k < 8; ++k) {
        const int i = t + 1024 * k;
        const float2 c = coords2[i];
        int cx = (int)(c.x * 64.0f); cx = min(max(cx, 0), G - 1);
        int cy = (int)(c.y * 64.0f); cy = min(max(cy, 0), G - 1);
        const unsigned pos = atomicAdd(&lhist[cy * G + cx], 1u);
        const float p0 = c.x * c.x;            // contract off: separate rn ops
        const float p1 = c.y * c.y;
        const float sc = p0 + p1;
        sorted[pos] = make_float4(c.x, c.y, sc, __int_as_float(i));
    }
}

// ---------------------------------------------------------------------------
// Kernel 2: query. 8 lanes/query. Step 1: 3x3 scan around clamped cell -> U.
// Step 2: exact candidate box from U (+MARGIN); skip if box within the 3x3,
// else scan per-row spans. Exact reference f32 d2, lex (d2,idx) update ->
// np.argmin semantics; unscanned points provably cannot beat or tie.
// ---------------------------------------------------------------------------
__global__ __launch_bounds__(256) void query_kernel(
    const float4* __restrict__ sorted,
    const int* __restrict__ starts,
    const float* __restrict__ spacing,
    const float* __restrict__ shift,
    int* __restrict__ nn_idx,
    float2* __restrict__ out_coords)
{
#pragma clang fp contract(off)
    const int lane = threadIdx.x & 7;
    const int q    = blockIdx.x * 32 + (threadIdx.x >> 3);   // [0, NQ)
    const int g    = q >> 13;
    const int k    = q & (N_PTS - 1);

    const float4 me = sorted[k];
    const int b = __float_as_int(me.w);     // original point index

    float nx, ny;
    shift_query(g, me.x, me.y, spacing[0], spacing[1], nx, ny);
    const float ax = nx - shift[0];
    const float ay = ny - shift[1];
    const float sa = (ax * ax) + (ay * ay);

    int cx = (int)floorf(ax * 64.0f); cx = min(max(cx, 0), G - 1);
    int cy = (int)floorf(ay * 64.0f); cy = min(max(cy, 0), G - 1);
    const float dxo = fmaxf(fmaxf(ax - 1.0f, -ax), 0.0f);   // x-overhang
    const float dyo = fmaxf(fmaxf(ay - 1.0f, -ay), 0.0f);   // y-overhang

    float best = INFINITY;
    int   bi   = 0x7fffffff;

#define EVAL_SPAN(S, E)                                                     \
    for (int i = (S) + lane; i < (E); i += 8) {                             \
        const float4 pt = sorted[i];                                        \
        const float p   = ax * pt.x;                                        \
        const float dv  = __builtin_fmaf(ay, pt.y, p);                      \
        const float t1  = sa + pt.z;                                        \
        const float d2  = t1 - (2.0f * dv);                                 \
        const int   j   = __float_as_int(pt.w);                             \
        if (d2 < best || (d2 == best && j < bi)) { best = d2; bi = j; }     \
    }

    // ---- step 1: 3x3 around clamped cell
    const int xa = max(cx - 1, 0), xb = min(cx + 1, G - 1);
    const int ya = max(cy - 1, 0), yb = min(cy + 1, G - 1);
    for (int yy = ya; yy <= yb; ++yy) {
        const int s = starts[yy * G + xa];
        const int e = starts[yy * G + xb + 1];
        EVAL_SPAN(s, e)
    }

    unsigned long long key =
        ((unsigned long long)fsortkey(best) << 32) | (unsigned int)bi;
    #pragma unroll
    for (int m = 1; m < 8; m <<= 1) {
        const unsigned long long o = __shfl_xor(key, m, 8);
        if (o < key) key = o;
    }
    best = finvkey((unsigned int)(key >> 32));
    bi   = (int)(unsigned int)key;

    // ---- step 2: exact candidate box from U = best + MARGIN
    const float U = best + MARGIN;

    // row range: vy^2 <= U - dxo^2  (U >= dd, so argument >= dyo^2 >= 0)
    float sr = sqrtf(fmaxf(U - dxo * dxo, 0.0f));
    sr = fminf(sr, 4.0f);                   // INF-safe; 4 covers whole grid
    const int ylo = max((int)floorf((ay - sr) * 64.0f), 0);
    const int yhi = min((int)floorf((ay + sr) * 64.0f), G - 1);

    // widest possible col range (at vy=0), for the skip test
    float sc_ = fminf(sqrtf(U), 4.0f);
    const int xlo_c = max((int)floorf((ax - sc_) * 64.0f), 0);
    const int xhi_c = min((int)floorf((ax + sc_) * 64.0f), G - 1);

    const bool skip = (ylo >= ya) && (yhi <= yb) && (xlo_c >= xa) && (xhi_c <= xb);

    if (!skip) {
        for (int yy = ylo; yy <= yhi; ++yy) {
            const float ry0 = (float)yy * HCELL;
            const float ry1 = ry0 + HCELL;
            const float vy  = fmaxf(fmaxf(ay - ry1, ry0 - ay), 0.0f);
            const float r2  = U - vy * vy;
            if (r2 < 0.0f) continue;
            float s = fminf(sqrtf(r2), 4.0f);
            const int xl = max((int)floorf((ax - s) * 64.0f), 0);
            const int xh = min((int)floorf((ax + s) * 64.0f), G - 1);
            const int ss = starts[yy * G + xl];
            const int ee = starts[yy * G + xh + 1];
            EVAL_SPAN(ss, ee)
        }
        key = ((unsigned long long)fsortkey(best) << 32) | (unsigned int)bi;
        #pragma unroll
        for (int m = 1; m < 8; m <<= 1) {
            const unsigned long long o = __shfl_xor(key, m, 8);
            if (o < key) key = o;
        }
    }
#undef EVAL_SPAN

    if (lane == 0) {
        const int qi = g * N_PTS + b;
        nn_idx[qi] = (int)(unsigned int)key;
        out_coords[N_PTS + qi] = make_float2(nx, ny);
    }
}

// ---------------------------------------------------------------------------
// Kernel 3: out_values all 4N rows (copy + gather) and out_coords rows [0,N).
// ---------------------------------------------------------------------------
__global__ __launch_bounds__(256) void gather_kernel(
    const float4* __restrict__ values4,
    const int* __restrict__ nn_idx,
    const float2* __restrict__ coords2,
    float4* __restrict__ out_values4,
    float2* __restrict__ out_coords)
{
    const int t   = blockIdx.x * 256 + threadIdx.x;
    const int row = t >> 4;
    const int c4  = t & 15;
    int src;
    if (row < N_PTS) {
        src = row;
        if (c4 == 0) out_coords[row] = coords2[row];
    } else {
        src = nn_idx[row - N_PTS];
    }
    out_values4[row * 16 + c4] = values4[src * 16 + c4];
}

extern "C" void kernel_launch(void* const* d_in, const int* in_sizes, int n_in,
                              void* d_out, int out_size, void* d_ws, size_t ws_size,
                              hipStream_t stream)
{
    const float* values  = (const float*)d_in[0];   // [8192,64]
    const float* coords  = (const float*)d_in[1];   // [8192,2]
    const float* spacing = (const float*)d_in[2];   // [2]
    const float* shift   = (const float*)d_in[3];   // [2]

    float* out_values = (float*)d_out;                          // [32768,64]
    float2* out_coords = (float2*)(out_values + (size_t)4 * N_PTS * C_DIM);

    char* ws = (char*)d_ws;
    float4* sorted = (float4*)ws;                   // @0
    int* starts    = (int*)(ws + 131072);
    int* nn_idx    = (int*)(ws + 147472);

    build_kernel<<<1, 1024, 0, stream>>>((const float2*)coords, sorted, starts);

    query_kernel<<<NQ / 32, 256, 0, stream>>>(
        sorted, starts, spacing, shift, nn_idx, out_coords);

    gather_kernel<<<(4 * N_PTS * 16) / 256, 256, 0, stream>>>(
        (const float4*)values, nn_idx, (const float2*)coords,
        (float4*)out_values, out_coords);
}

// Round 9
// 26.969 us; speedup vs baseline: 16.2698x; 1.1105x over previous
//
#include <hip/hip_runtime.h>

// numpy rounds every op separately — keep contraction off everywhere.
#pragma clang fp contract(off)

#define N_PTS 8192
#define C_DIM 64
#define NQ (3 * N_PTS)          // 24576 queries
#define G 64                    // grid cells per axis
#define NCELL (G * G)           // 4096
#define MARGIN 1.2e-5f          // >> 2*E(f32 formula ~3.5e-6) + binning/fp slop
#define HCELL (1.0f / 64.0f)
#define QBLOCKS (NQ / 32)       // 768 query blocks
#define CBLOCKS 256             // copy blocks (32 value-rows each)

// ws layout:
//   sorted   float4[8192]  @ 0        (cx, cy, sc, idx-bits)
//   starts   int[4097]     @ 131072

__device__ __forceinline__ unsigned int fsortkey(float f) {
    const unsigned int u = __float_as_uint(f);
    return (u & 0x80000000u) ? ~u : (u | 0x80000000u);
}
__device__ __forceinline__ float finvkey(unsigned int e) {
    const unsigned int u = (e & 0x80000000u) ? (e & 0x7fffffffu) : ~e;
    return __uint_as_float(u);
}

__device__ __forceinline__ void shift_query(int g, float x, float y,
                                            float sx, float sy,
                                            float& nx, float& ny) {
    if (g == 0)      { nx = x + sx; ny = y + sy; }
    else if (g == 1) { nx = x;      ny = y + sy; }
    else             { nx = x + sx; ny = y; }
}

// ---------------------------------------------------------------------------
// Kernel 1: single-block counting sort into 64x64 cells. Scan de-serialized:
// wave-level shfl_up inclusive scan + 16 wave-sums scanned in wave 0.
// 5 barriers total (was ~23).
// ---------------------------------------------------------------------------
__global__ __launch_bounds__(1024) void build_kernel(
    const float2* __restrict__ coords2,
    float4* __restrict__ sorted,
    int* __restrict__ starts)
{
#pragma clang fp contract(off)
    __shared__ unsigned int lhist[NCELL];   // 16 KB
    __shared__ unsigned int wsum[16];
    const int t    = threadIdx.x;
    const int lane = t & 63;
    const int w    = t >> 6;

    #pragma unroll
    for (int k = 0; k < 4; ++k) lhist[4 * t + k] = 0u;
    __syncthreads();

    #pragma unroll
    for (int k = 0; k < 8; ++k) {
        const int i = t + 1024 * k;
        const float2 c = coords2[i];
        int cx = (int)(c.x * 64.0f); cx = min(max(cx, 0), G - 1);
        int cy = (int)(c.y * 64.0f); cy = min(max(cy, 0), G - 1);
        atomicAdd(&lhist[cy * G + cx], 1u);
    }
    __syncthreads();

    const unsigned h0 = lhist[4 * t + 0], h1 = lhist[4 * t + 1];
    const unsigned h2 = lhist[4 * t + 2], h3 = lhist[4 * t + 3];
    const unsigned tot = h0 + h1 + h2 + h3;

    // inclusive scan within wave (shfl_up, no barriers)
    unsigned v = tot;
    #pragma unroll
    for (int s = 1; s < 64; s <<= 1) {
        const unsigned o = __shfl_up(v, s, 64);
        if (lane >= s) v += o;
    }
    if (lane == 63) wsum[w] = v;
    __syncthreads();
    if (t < 16) {                   // scan the 16 wave totals in wave 0
        unsigned x = wsum[t];
        #pragma unroll
        for (int s = 1; s < 16; s <<= 1) {
            const unsigned o = __shfl_up(x, s, 16);
            if ((t & 15) >= s) x += o;
        }
        wsum[t] = x;                // inclusive
    }
    __syncthreads();
    const unsigned woff = (w == 0) ? 0u : wsum[w - 1];
    const unsigned e0 = v + woff - tot;     // global exclusive start
    const unsigned e1 = e0 + h0, e2 = e1 + h1, e3 = e2 + h2;
    starts[4 * t + 0] = (int)e0; starts[4 * t + 1] = (int)e1;
    starts[4 * t + 2] = (int)e2; starts[4 * t + 3] = (int)e3;
    lhist[4 * t + 0] = e0; lhist[4 * t + 1] = e1;
    lhist[4 * t + 2] = e2; lhist[4 * t + 3] = e3;
    if (t == 0) starts[NCELL] = N_PTS;
    __syncthreads();

    #pragma unroll
    for (int k = 0; k < 8; ++k) {
        const int i = t + 1024 * k;
        const float2 c = coords2[i];
        int cx = (int)(c.x * 64.0f); cx = min(max(cx, 0), G - 1);
        int cy = (int)(c.y * 64.0f); cy = min(max(cy, 0), G - 1);
        const unsigned pos = atomicAdd(&lhist[cy * G + cx], 1u);
        const float p0 = c.x * c.x;            // contract off: separate rn ops
        const float p1 = c.y * c.y;
        const float sc = p0 + p1;
        sorted[pos] = make_float4(c.x, c.y, sc, __int_as_float(i));
    }
}

// ---------------------------------------------------------------------------
// Kernel 2 (mega): blocks [0,768): 32 queries each — round-8 verified search
// (3x3 scan -> U; exact candidate box; lex (d2,idx) reduce), then all 8 lanes
// gather values[bi] and write the output row directly. Blocks [768,1024):
// copy 32 original value-rows + original coords each.
// ---------------------------------------------------------------------------
__global__ __launch_bounds__(256) void mega_kernel(
    const float4* __restrict__ sorted,
    const int* __restrict__ starts,
    const float4* __restrict__ values4,
    const float2* __restrict__ coords2,
    const float* __restrict__ spacing,
    const float* __restrict__ shift,
    float4* __restrict__ out_values4,
    float2* __restrict__ out_coords)
{
#pragma clang fp contract(off)
    if (blockIdx.x >= QBLOCKS) {
        // ---- copy path: original values rows + original coords
        const int blk = blockIdx.x - QBLOCKS;      // 0..255
        const int c4  = threadIdx.x & 15;
        #pragma unroll
        for (int it = 0; it < 2; ++it) {
            const int row = blk * 32 + it * 16 + (threadIdx.x >> 4);
            out_values4[row * 16 + c4] = values4[row * 16 + c4];
            if (c4 == 0) out_coords[row] = coords2[row];
        }
        return;
    }

    const int lane = threadIdx.x & 7;
    const int q    = blockIdx.x * 32 + (threadIdx.x >> 3);   // [0, NQ)
    const int g    = q >> 13;
    const int k    = q & (N_PTS - 1);

    const float4 me = sorted[k];
    const int b = __float_as_int(me.w);     // original point index

    float nx, ny;
    shift_query(g, me.x, me.y, spacing[0], spacing[1], nx, ny);
    const float ax = nx - shift[0];
    const float ay = ny - shift[1];
    const float sa = (ax * ax) + (ay * ay);

    int cx = (int)floorf(ax * 64.0f); cx = min(max(cx, 0), G - 1);
    int cy = (int)floorf(ay * 64.0f); cy = min(max(cy, 0), G - 1);
    const float dxo = fmaxf(fmaxf(ax - 1.0f, -ax), 0.0f);   // x-overhang
    const float dyo = fmaxf(fmaxf(ay - 1.0f, -ay), 0.0f);   // (kept for clarity)
    (void)dyo;

    float best = INFINITY;
    int   bi   = 0x7fffffff;

#define EVAL_SPAN(S, E)                                                     \
    for (int i = (S) + lane; i < (E); i += 8) {                             \
        const float4 pt = sorted[i];                                        \
        const float p   = ax * pt.x;                                        \
        const float dv  = __builtin_fmaf(ay, pt.y, p);                      \
        const float t1  = sa + pt.z;                                        \
        const float d2  = t1 - (2.0f * dv);                                 \
        const int   j   = __float_as_int(pt.w);                             \
        if (d2 < best || (d2 == best && j < bi)) { best = d2; bi = j; }     \
    }

    // ---- step 1: 3x3 around clamped cell
    const int xa = max(cx - 1, 0), xb = min(cx + 1, G - 1);
    const int ya = max(cy - 1, 0), yb = min(cy + 1, G - 1);
    for (int yy = ya; yy <= yb; ++yy) {
        const int s = starts[yy * G + xa];
        const int e = starts[yy * G + xb + 1];
        EVAL_SPAN(s, e)
    }

    unsigned long long key =
        ((unsigned long long)fsortkey(best) << 32) | (unsigned int)bi;
    #pragma unroll
    for (int m = 1; m < 8; m <<= 1) {
        const unsigned long long o = __shfl_xor(key, m, 8);
        if (o < key) key = o;
    }
    best = finvkey((unsigned int)(key >> 32));
    bi   = (int)(unsigned int)key;

    // ---- step 2: exact candidate box from U = best + MARGIN
    const float U = best + MARGIN;

    float sr = sqrtf(fmaxf(U - dxo * dxo, 0.0f));
    sr = fminf(sr, 4.0f);                   // INF-safe; 4 covers whole grid
    const int ylo = max((int)floorf((ay - sr) * 64.0f), 0);
    const int yhi = min((int)floorf((ay + sr) * 64.0f), G - 1);

    float sc_ = fminf(sqrtf(U), 4.0f);
    const int xlo_c = max((int)floorf((ax - sc_) * 64.0f), 0);
    const int xhi_c = min((int)floorf((ax + sc_) * 64.0f), G - 1);

    const bool skip = (ylo >= ya) && (yhi <= yb) && (xlo_c >= xa) && (xhi_c <= xb);

    if (!skip) {
        for (int yy = ylo; yy <= yhi; ++yy) {
            const float ry0 = (float)yy * HCELL;
            const float ry1 = ry0 + HCELL;
            const float vy  = fmaxf(fmaxf(ay - ry1, ry0 - ay), 0.0f);
            const float r2  = U - vy * vy;
            if (r2 < 0.0f) continue;
            float s = fminf(sqrtf(r2), 4.0f);
            const int xl = max((int)floorf((ax - s) * 64.0f), 0);
            const int xh = min((int)floorf((ax + s) * 64.0f), G - 1);
            const int ss = starts[yy * G + xl];
            const int ee = starts[yy * G + xh + 1];
            EVAL_SPAN(ss, ee)
        }
        key = ((unsigned long long)fsortkey(best) << 32) | (unsigned int)bi;
        #pragma unroll
        for (int m = 1; m < 8; m <<= 1) {
            const unsigned long long o = __shfl_xor(key, m, 8);
            if (o < key) key = o;
        }
        bi = (int)(unsigned int)key;
    }
#undef EVAL_SPAN

    // ---- fused gather: all 8 lanes have the winning bi; write the row
    const int qi  = g * N_PTS + b;
    const int row = N_PTS + qi;
    out_values4[row * 16 + 2 * lane + 0] = values4[bi * 16 + 2 * lane + 0];
    out_values4[row * 16 + 2 * lane + 1] = values4[bi * 16 + 2 * lane + 1];
    if (lane == 0) out_coords[row] = make_float2(nx, ny);
}

extern "C" void kernel_launch(void* const* d_in, const int* in_sizes, int n_in,
                              void* d_out, int out_size, void* d_ws, size_t ws_size,
                              hipStream_t stream)
{
    const float* values  = (const float*)d_in[0];   // [8192,64]
    const float* coords  = (const float*)d_in[1];   // [8192,2]
    const float* spacing = (const float*)d_in[2];   // [2]
    const float* shift   = (const float*)d_in[3];   // [2]

    float* out_values = (float*)d_out;                          // [32768,64]
    float2* out_coords = (float2*)(out_values + (size_t)4 * N_PTS * C_DIM);

    char* ws = (char*)d_ws;
    float4* sorted = (float4*)ws;                   // @0
    int* starts    = (int*)(ws + 131072);

    build_kernel<<<1, 1024, 0, stream>>>((const float2*)coords, sorted, starts);

    mega_kernel<<<QBLOCKS + CBLOCKS, 256, 0, stream>>>(
        sorted, starts, (const float4*)values, (const float2*)coords,
        spacing, shift, (float4*)out_values, out_coords);
}

// Round 10
// 24.595 us; speedup vs baseline: 17.8404x; 1.0965x over previous
//
#include <hip/hip_runtime.h>

// numpy rounds every op separately — keep contraction off everywhere.
#pragma clang fp contract(off)

#define N_PTS 8192
#define C_DIM 64
#define NQ (3 * N_PTS)          // 24576 queries
#define G 64                    // grid cells per axis
#define NCELL (G * G)           // 4096
#define MARGIN 1.2e-5f          // >> 2*E(f32 formula ~3.5e-6) + binning/fp slop
#define HCELL (1.0f / 64.0f)
#define QBLOCKS (NQ / 32)       // 768 query blocks
#define COPYBLKS 128            // copy blocks (64 value-rows each)

// ws layout:
//   sorted   float4[8192]  @ 0        (cx, cy, sc, idx-bits)
//   starts   int[4097]     @ 131072

__device__ __forceinline__ unsigned int fsortkey(float f) {
    const unsigned int u = __float_as_uint(f);
    return (u & 0x80000000u) ? ~u : (u | 0x80000000u);
}
__device__ __forceinline__ float finvkey(unsigned int e) {
    const unsigned int u = (e & 0x80000000u) ? (e & 0x7fffffffu) : ~e;
    return __uint_as_float(u);
}

__device__ __forceinline__ void shift_query(int g, float x, float y,
                                            float sx, float sy,
                                            float& nx, float& ny) {
    if (g == 0)      { nx = x + sx; ny = y + sy; }
    else if (g == 1) { nx = x;      ny = y + sy; }
    else             { nx = x + sx; ny = y; }
}

// ---------------------------------------------------------------------------
// Kernel 1: block 0 = single-block counting sort (verified r6-r9, with coords
// register-cached between phases). Blocks 1..128 = copy of the original 8192
// value rows + original coords (runs on other CUs, hidden under the build).
// ---------------------------------------------------------------------------
__global__ __launch_bounds__(1024) void build_copy_kernel(
    const float2* __restrict__ coords2,
    const float4* __restrict__ values4,
    float4* __restrict__ sorted,
    int* __restrict__ starts,
    float4* __restrict__ out_values4,
    float2* __restrict__ out_coords)
{
#pragma clang fp contract(off)
    if (blockIdx.x > 0) {
        // ---- copy path: 64 rows per block, 16 lanes per row
        const int t   = threadIdx.x;
        const int row = ((int)blockIdx.x - 1) * 64 + (t >> 4);
        const int c4  = t & 15;
        out_values4[row * 16 + c4] = values4[row * 16 + c4];
        if (c4 == 0) out_coords[row] = coords2[row];
        return;
    }

    __shared__ unsigned int lhist[NCELL];   // 16 KB
    __shared__ unsigned int wsum[16];
    const int t    = threadIdx.x;
    const int lane = t & 63;
    const int w    = t >> 6;

    #pragma unroll
    for (int k = 0; k < 4; ++k) lhist[4 * t + k] = 0u;
    __syncthreads();

    float2 cpt[8];
    int    cell[8];
    #pragma unroll
    for (int k = 0; k < 8; ++k) {
        const int i = t + 1024 * k;
        const float2 c = coords2[i];
        cpt[k] = c;
        int cx = (int)(c.x * 64.0f); cx = min(max(cx, 0), G - 1);
        int cy = (int)(c.y * 64.0f); cy = min(max(cy, 0), G - 1);
        cell[k] = cy * G + cx;
        atomicAdd(&lhist[cell[k]], 1u);
    }
    __syncthreads();

    const unsigned h0 = lhist[4 * t + 0], h1 = lhist[4 * t + 1];
    const unsigned h2 = lhist[4 * t + 2], h3 = lhist[4 * t + 3];
    const unsigned tot = h0 + h1 + h2 + h3;

    // inclusive scan within wave (shfl_up, no barriers)
    unsigned v = tot;
    #pragma unroll
    for (int s = 1; s < 64; s <<= 1) {
        const unsigned o = __shfl_up(v, s, 64);
        if (lane >= s) v += o;
    }
    if (lane == 63) wsum[w] = v;
    __syncthreads();
    if (t < 16) {                   // scan the 16 wave totals in wave 0
        unsigned x = wsum[t];
        #pragma unroll
        for (int s = 1; s < 16; s <<= 1) {
            const unsigned o = __shfl_up(x, s, 16);
            if ((t & 15) >= s) x += o;
        }
        wsum[t] = x;                // inclusive
    }
    __syncthreads();
    const unsigned woff = (w == 0) ? 0u : wsum[w - 1];
    const unsigned e0 = v + woff - tot;     // global exclusive start
    const unsigned e1 = e0 + h0, e2 = e1 + h1, e3 = e2 + h2;
    starts[4 * t + 0] = (int)e0; starts[4 * t + 1] = (int)e1;
    starts[4 * t + 2] = (int)e2; starts[4 * t + 3] = (int)e3;
    lhist[4 * t + 0] = e0; lhist[4 * t + 1] = e1;
    lhist[4 * t + 2] = e2; lhist[4 * t + 3] = e3;
    if (t == 0) starts[NCELL] = N_PTS;
    __syncthreads();

    #pragma unroll
    for (int k = 0; k < 8; ++k) {
        const int i = t + 1024 * k;
        const float2 c = cpt[k];
        const unsigned pos = atomicAdd(&lhist[cell[k]], 1u);
        const float p0 = c.x * c.x;            // contract off: separate rn ops
        const float p1 = c.y * c.y;
        const float sc = p0 + p1;
        sorted[pos] = make_float4(c.x, c.y, sc, __int_as_float(i));
    }
}

// ---------------------------------------------------------------------------
// Kernel 2: queries. 8 lanes/query. Step 1: 3x3 scan around clamped cell
// (all row bounds prefetched in parallel) -> U. Step 2: exact candidate box
// from U+MARGIN, rows batched 4-wide with parallel bound prefetch; rows fully
// covered by the 3x3 are skipped (already scanned). Exact reference f32 d2,
// lex (d2,idx) -> np.argmin semantics; scanned-cell union identical to r8/r9.
// Fused gather of the winning values row.
// ---------------------------------------------------------------------------
__global__ __launch_bounds__(256) void query_kernel(
    const float4* __restrict__ sorted,
    const int* __restrict__ starts,
    const float4* __restrict__ values4,
    const float* __restrict__ spacing,
    const float* __restrict__ shift,
    float4* __restrict__ out_values4,
    float2* __restrict__ out_coords)
{
#pragma clang fp contract(off)
    const int lane = threadIdx.x & 7;
    const int q    = blockIdx.x * 32 + (threadIdx.x >> 3);   // [0, NQ)
    const int g    = q >> 13;
    const int k    = q & (N_PTS - 1);

    const float4 me = sorted[k];
    const int b = __float_as_int(me.w);     // original point index

    float nx, ny;
    shift_query(g, me.x, me.y, spacing[0], spacing[1], nx, ny);
    const float ax = nx - shift[0];
    const float ay = ny - shift[1];
    const float sa = (ax * ax) + (ay * ay);

    int cx = (int)floorf(ax * 64.0f); cx = min(max(cx, 0), G - 1);
    int cy = (int)floorf(ay * 64.0f); cy = min(max(cy, 0), G - 1);
    const float dxo = fmaxf(fmaxf(ax - 1.0f, -ax), 0.0f);   // x-overhang

    float best = INFINITY;
    int   bi   = 0x7fffffff;

#define EVAL_SPAN(S, E)                                                     \
    for (int i = (S) + lane; i < (E); i += 8) {                             \
        const float4 pt = sorted[i];                                        \
        const float p   = ax * pt.x;                                        \
        const float dv  = __builtin_fmaf(ay, pt.y, p);                      \
        const float t1  = sa + pt.z;                                        \
        const float d2  = t1 - (2.0f * dv);                                 \
        const int   j   = __float_as_int(pt.w);                             \
        if (d2 < best || (d2 == best && j < bi)) { best = d2; bi = j; }     \
    }

    // ---- step 1: 3x3 around clamped cell; prefetch all row bounds first
    const int xa = max(cx - 1, 0), xb = min(cx + 1, G - 1);
    const int ya = max(cy - 1, 0), yb = min(cy + 1, G - 1);
    int ss1[3], ee1[3];
    #pragma unroll
    for (int r = 0; r < 3; ++r) {
        const int yy = ya + r;
        const bool vv = (yy <= yb);
        ss1[r] = vv ? starts[yy * G + xa] : 0;
        ee1[r] = vv ? starts[yy * G + xb + 1] : 0;
    }
    #pragma unroll
    for (int r = 0; r < 3; ++r) {
        EVAL_SPAN(ss1[r], ee1[r])
    }

    unsigned long long key =
        ((unsigned long long)fsortkey(best) << 32) | (unsigned int)bi;
    #pragma unroll
    for (int m = 1; m < 8; m <<= 1) {
        const unsigned long long o = __shfl_xor(key, m, 8);
        if (o < key) key = o;
    }
    best = finvkey((unsigned int)(key >> 32));
    bi   = (int)(unsigned int)key;

    // ---- step 2: exact candidate box from U = best + MARGIN
    const float U = best + MARGIN;

    float sr = sqrtf(fmaxf(U - dxo * dxo, 0.0f));
    sr = fminf(sr, 4.0f);                   // INF-safe; 4 covers whole grid
    const int ylo = max((int)floorf((ay - sr) * 64.0f), 0);
    const int yhi = min((int)floorf((ay + sr) * 64.0f), G - 1);

    float scw = fminf(sqrtf(U), 4.0f);
    const int xlo_c = max((int)floorf((ax - scw) * 64.0f), 0);
    const int xhi_c = min((int)floorf((ax + scw) * 64.0f), G - 1);

    const bool skip = (ylo >= ya) && (yhi <= yb) && (xlo_c >= xa) && (xhi_c <= xb);

    if (!skip) {
        for (int yy0 = ylo; yy0 <= yhi; yy0 += 4) {
            int ss2[4], ee2[4];
            #pragma unroll
            for (int r = 0; r < 4; ++r) {
                const int yy = yy0 + r;
                bool vv = (yy <= yhi);
                const float ry0 = (float)yy * HCELL;
                const float vy  = fmaxf(fmaxf(ay - ry0 - HCELL, ry0 - ay), 0.0f);
                const float r2  = U - vy * vy;
                vv = vv && (r2 >= 0.0f);
                const float s = fminf(sqrtf(fmaxf(r2, 0.0f)), 4.0f);
                int xl = max((int)floorf((ax - s) * 64.0f), 0);
                int xh = min((int)floorf((ax + s) * 64.0f), G - 1);
                vv = vv && (xl <= xh);
                // rows fully inside the already-scanned 3x3: skip
                vv = vv && !(yy >= ya && yy <= yb && xl >= xa && xh <= xb);
                ss2[r] = vv ? starts[yy * G + xl] : 0;
                ee2[r] = vv ? starts[yy * G + xh + 1] : 0;
            }
            #pragma unroll
            for (int r = 0; r < 4; ++r) {
                EVAL_SPAN(ss2[r], ee2[r])
            }
        }
        key = ((unsigned long long)fsortkey(best) << 32) | (unsigned int)bi;
        #pragma unroll
        for (int m = 1; m < 8; m <<= 1) {
            const unsigned long long o = __shfl_xor(key, m, 8);
            if (o < key) key = o;
        }
        bi = (int)(unsigned int)key;
    }
#undef EVAL_SPAN

    // ---- fused gather: all 8 lanes have the winning bi; write the row
    const int qi  = g * N_PTS + b;
    const int row = N_PTS + qi;
    out_values4[row * 16 + 2 * lane + 0] = values4[bi * 16 + 2 * lane + 0];
    out_values4[row * 16 + 2 * lane + 1] = values4[bi * 16 + 2 * lane + 1];
    if (lane == 0) out_coords[row] = make_float2(nx, ny);
}

extern "C" void kernel_launch(void* const* d_in, const int* in_sizes, int n_in,
                              void* d_out, int out_size, void* d_ws, size_t ws_size,
                              hipStream_t stream)
{
    const float* values  = (const float*)d_in[0];   // [8192,64]
    const float* coords  = (const float*)d_in[1];   // [8192,2]
    const float* spacing = (const float*)d_in[2];   // [2]
    const float* shift   = (const float*)d_in[3];   // [2]

    float* out_values = (float*)d_out;                          // [32768,64]
    float2* out_coords = (float2*)(out_values + (size_t)4 * N_PTS * C_DIM);

    char* ws = (char*)d_ws;
    float4* sorted = (float4*)ws;                   // @0
    int* starts    = (int*)(ws + 131072);

    build_copy_kernel<<<1 + COPYBLKS, 1024, 0, stream>>>(
        (const float2*)coords, (const float4*)values,
        sorted, starts, (float4*)out_values, out_coords);

    query_kernel<<<QBLOCKS, 256, 0, stream>>>(
        sorted, starts, (const float4*)values, spacing, shift,
        (float4*)out_values, out_coords);
}

// Round 11
// 23.558 us; speedup vs baseline: 18.6256x; 1.0440x over previous
//
#include <hip/hip_runtime.h>

// numpy rounds every op separately — keep contraction off everywhere.
#pragma clang fp contract(off)

#define N_PTS 8192
#define C_DIM 64
#define NQ (3 * N_PTS)          // 24576 queries
#define G 64                    // grid cells per axis
#define NCELL (G * G)           // 4096
#define MARGIN 1.2e-5f          // >> 2*E(f32 formula ~3.5e-6) + binning/fp slop
#define HCELL (1.0f / 64.0f)
#define QBLOCKS (NQ / 32)       // 768 query blocks
#define STRIPEBLKS 16           // build stripes (4 cell-rows each)
#define CPS (NCELL / STRIPEBLKS)// 256 cells per stripe
#define COPYBLKS 128            // copy blocks (64 value-rows each)

// ws layout:
//   sorted   float4[8192]  @ 0        (cx, cy, sc, idx-bits)
//   starts   int[4097]     @ 131072

__device__ __forceinline__ unsigned int fsortkey(float f) {
    const unsigned int u = __float_as_uint(f);
    return (u & 0x80000000u) ? ~u : (u | 0x80000000u);
}
__device__ __forceinline__ float finvkey(unsigned int e) {
    const unsigned int u = (e & 0x80000000u) ? (e & 0x7fffffffu) : ~e;
    return __uint_as_float(u);
}

__device__ __forceinline__ void shift_query(int g, float x, float y,
                                            float sx, float sy,
                                            float& nx, float& ny) {
    if (g == 0)      { nx = x + sx; ny = y + sy; }
    else if (g == 1) { nx = x;      ny = y + sy; }
    else             { nx = x + sx; ny = y; }
}

// ---------------------------------------------------------------------------
// Kernel 1: blocks [0,16): striped counting sort — block b owns cells
// [b*256,(b+1)*256). Base offset computed locally as count(cell < myBase)
// (stripes are contiguous in cell index -> no inter-block communication).
// Blocks [16,144): copy original value rows + original coords.
// ---------------------------------------------------------------------------
__global__ __launch_bounds__(1024) void build_copy_kernel(
    const float2* __restrict__ coords2,
    const float4* __restrict__ values4,
    float4* __restrict__ sorted,
    int* __restrict__ starts,
    float4* __restrict__ out_values4,
    float2* __restrict__ out_coords)
{
#pragma clang fp contract(off)
    const int t = threadIdx.x;
    if (blockIdx.x >= STRIPEBLKS) {
        // ---- copy path: 64 rows per block, 16 lanes per row
        const int row = ((int)blockIdx.x - STRIPEBLKS) * 64 + (t >> 4);
        const int c4  = t & 15;
        out_values4[row * 16 + c4] = values4[row * 16 + c4];
        if (c4 == 0) out_coords[row] = coords2[row];
        return;
    }

    __shared__ unsigned int lhist[CPS];     // 1 KB
    __shared__ unsigned int wred[16];
    __shared__ unsigned int wsum2[4];
    __shared__ unsigned int baseSh;

    const int b      = blockIdx.x;
    const int myBase = b * CPS;
    const int lane   = t & 63;
    const int w      = t >> 6;

    if (t < CPS) lhist[t] = 0u;
    __syncthreads();

    // pass 1: read all coords; histogram my stripe; count points below me
    float2 cpt[8];
    int    cell[8];
    int cnt = 0;
    #pragma unroll
    for (int k = 0; k < 8; ++k) {
        const int i = t + 1024 * k;
        const float2 c = coords2[i];
        cpt[k] = c;
        int cx = (int)(c.x * 64.0f); cx = min(max(cx, 0), G - 1);
        int cy = (int)(c.y * 64.0f); cy = min(max(cy, 0), G - 1);
        cell[k] = cy * G + cx;
        cnt += (cell[k] < myBase) ? 1 : 0;
        const int lc = cell[k] - myBase;
        if (lc >= 0 && lc < CPS) atomicAdd(&lhist[lc], 1u);
    }

    // block-reduce cnt -> base
    int cv = cnt;
    #pragma unroll
    for (int s = 32; s >= 1; s >>= 1) cv += __shfl_xor(cv, s, 64);
    if (lane == 0) wred[w] = (unsigned)cv;
    __syncthreads();
    if (t == 0) {
        unsigned s = 0;
        #pragma unroll
        for (int j = 0; j < 16; ++j) s += wred[j];
        baseSh = s;
    }
    __syncthreads();
    const unsigned base = baseSh;

    // scan my 256 cell counts (threads 0..255, waves 0..3)
    unsigned h = 0, v = 0;
    if (t < CPS) {
        h = lhist[t];
        v = h;
        #pragma unroll
        for (int s = 1; s < 64; s <<= 1) {
            const unsigned o = __shfl_up(v, s, 64);
            if (lane >= s) v += o;
        }
        if (lane == 63) wsum2[w] = v;
    }
    __syncthreads();
    if (t < CPS) {
        unsigned woff = 0;
        for (int j = 0; j < w; ++j) woff += wsum2[j];
        const unsigned excl = base + woff + v - h;
        starts[myBase + t] = (int)excl;
        lhist[t] = excl;                    // becomes the scatter cursor
    }
    if (b == 0 && t == 0) starts[NCELL] = N_PTS;
    __syncthreads();

    // pass 2: scatter my stripe's points
    #pragma unroll
    for (int k = 0; k < 8; ++k) {
        const int lc = cell[k] - myBase;
        if (lc >= 0 && lc < CPS) {
            const unsigned pos = atomicAdd(&lhist[lc], 1u);
            const float p0 = cpt[k].x * cpt[k].x;   // separate rn ops
            const float p1 = cpt[k].y * cpt[k].y;
            const float sc = p0 + p1;
            const int i = t + 1024 * k;
            sorted[pos] = make_float4(cpt[k].x, cpt[k].y, sc, __int_as_float(i));
        }
    }
}

// ---------------------------------------------------------------------------
// Kernel 2: queries. 8 lanes/query; full starts table cached in LDS.
// Step 1: 3x3 scan around clamped cell -> U. Step 2: exact candidate box from
// U+MARGIN (rows batched 4-wide; rows covered by the 3x3 skipped). Exact
// reference f32 d2, lex (d2,idx) -> np.argmin semantics. Fused row gather.
// ---------------------------------------------------------------------------
__global__ __launch_bounds__(256) void query_kernel(
    const float4* __restrict__ sorted,
    const int* __restrict__ starts,
    const float4* __restrict__ values4,
    const float* __restrict__ spacing,
    const float* __restrict__ shift,
    float4* __restrict__ out_values4,
    float2* __restrict__ out_coords)
{
#pragma clang fp contract(off)
    __shared__ int s_starts[NCELL + 1];     // 16388 B

    const int tid  = threadIdx.x;
    const int lane = tid & 7;
    const int q    = blockIdx.x * 32 + (tid >> 3);   // [0, NQ)
    const int g    = q >> 13;
    const int k    = q & (N_PTS - 1);

    const float4 me = sorted[k];            // issue early, overlaps staging

    for (int i = tid; i <= NCELL; i += 256) s_starts[i] = starts[i];

    const int b = __float_as_int(me.w);     // original point index
    float nx, ny;
    shift_query(g, me.x, me.y, spacing[0], spacing[1], nx, ny);
    const float ax = nx - shift[0];
    const float ay = ny - shift[1];
    const float sa = (ax * ax) + (ay * ay);

    int cx = (int)floorf(ax * 64.0f); cx = min(max(cx, 0), G - 1);
    int cy = (int)floorf(ay * 64.0f); cy = min(max(cy, 0), G - 1);
    const float dxo = fmaxf(fmaxf(ax - 1.0f, -ax), 0.0f);   // x-overhang

    __syncthreads();

    float best = INFINITY;
    int   bi   = 0x7fffffff;

#define EVAL_SPAN(S, E)                                                     \
    for (int i = (S) + lane; i < (E); i += 8) {                             \
        const float4 pt = sorted[i];                                        \
        const float p   = ax * pt.x;                                        \
        const float dv  = __builtin_fmaf(ay, pt.y, p);                      \
        const float t1  = sa + pt.z;                                        \
        const float d2  = t1 - (2.0f * dv);                                 \
        const int   j   = __float_as_int(pt.w);                             \
        if (d2 < best || (d2 == best && j < bi)) { best = d2; bi = j; }     \
    }

    // ---- step 1: 3x3 around clamped cell (bounds from LDS)
    const int xa = max(cx - 1, 0), xb = min(cx + 1, G - 1);
    const int ya = max(cy - 1, 0), yb = min(cy + 1, G - 1);
    int ss1[3], ee1[3];
    #pragma unroll
    for (int r = 0; r < 3; ++r) {
        const int yy = ya + r;
        const bool vv = (yy <= yb);
        ss1[r] = vv ? s_starts[yy * G + xa] : 0;
        ee1[r] = vv ? s_starts[yy * G + xb + 1] : 0;
    }
    #pragma unroll
    for (int r = 0; r < 3; ++r) {
        EVAL_SPAN(ss1[r], ee1[r])
    }

    unsigned long long key =
        ((unsigned long long)fsortkey(best) << 32) | (unsigned int)bi;
    #pragma unroll
    for (int m = 1; m < 8; m <<= 1) {
        const unsigned long long o = __shfl_xor(key, m, 8);
        if (o < key) key = o;
    }
    best = finvkey((unsigned int)(key >> 32));
    bi   = (int)(unsigned int)key;

    // ---- step 2: exact candidate box from U = best + MARGIN
    const float U = best + MARGIN;

    float sr = sqrtf(fmaxf(U - dxo * dxo, 0.0f));
    sr = fminf(sr, 4.0f);                   // INF-safe; 4 covers whole grid
    const int ylo = max((int)floorf((ay - sr) * 64.0f), 0);
    const int yhi = min((int)floorf((ay + sr) * 64.0f), G - 1);

    float scw = fminf(sqrtf(U), 4.0f);
    const int xlo_c = max((int)floorf((ax - scw) * 64.0f), 0);
    const int xhi_c = min((int)floorf((ax + scw) * 64.0f), G - 1);

    const bool skip = (ylo >= ya) && (yhi <= yb) && (xlo_c >= xa) && (xhi_c <= xb);

    if (!skip) {
        for (int yy0 = ylo; yy0 <= yhi; yy0 += 4) {
            int ss2[4], ee2[4];
            #pragma unroll
            for (int r = 0; r < 4; ++r) {
                const int yy = yy0 + r;
                bool vv = (yy <= yhi);
                const float ry0 = (float)yy * HCELL;
                const float vy  = fmaxf(fmaxf(ay - ry0 - HCELL, ry0 - ay), 0.0f);
                const float r2  = U - vy * vy;
                vv = vv && (r2 >= 0.0f);
                const float s = fminf(sqrtf(fmaxf(r2, 0.0f)), 4.0f);
                int xl = max((int)floorf((ax - s) * 64.0f), 0);
                int xh = min((int)floorf((ax + s) * 64.0f), G - 1);
                vv = vv && (xl <= xh);
                vv = vv && !(yy >= ya && yy <= yb && xl >= xa && xh <= xb);
                ss2[r] = vv ? s_starts[yy * G + xl] : 0;
                ee2[r] = vv ? s_starts[yy * G + xh + 1] : 0;
            }
            #pragma unroll
            for (int r = 0; r < 4; ++r) {
                EVAL_SPAN(ss2[r], ee2[r])
            }
        }
        key = ((unsigned long long)fsortkey(best) << 32) | (unsigned int)bi;
        #pragma unroll
        for (int m = 1; m < 8; m <<= 1) {
            const unsigned long long o = __shfl_xor(key, m, 8);
            if (o < key) key = o;
        }
        bi = (int)(unsigned int)key;
    }
#undef EVAL_SPAN

    // ---- fused gather: all 8 lanes have the winning bi; write the row
    const int qi  = g * N_PTS + b;
    const int row = N_PTS + qi;
    out_values4[row * 16 + 2 * lane + 0] = values4[bi * 16 + 2 * lane + 0];
    out_values4[row * 16 + 2 * lane + 1] = values4[bi * 16 + 2 * lane + 1];
    if (lane == 0) out_coords[row] = make_float2(nx, ny);
}

extern "C" void kernel_launch(void* const* d_in, const int* in_sizes, int n_in,
                              void* d_out, int out_size, void* d_ws, size_t ws_size,
                              hipStream_t stream)
{
    const float* values  = (const float*)d_in[0];   // [8192,64]
    const float* coords  = (const float*)d_in[1];   // [8192,2]
    const float* spacing = (const float*)d_in[2];   // [2]
    const float* shift   = (const float*)d_in[3];   // [2]

    float* out_values = (float*)d_out;                          // [32768,64]
    float2* out_coords = (float2*)(out_values + (size_t)4 * N_PTS * C_DIM);

    char* ws = (char*)d_ws;
    float4* sorted = (float4*)ws;                   // @0
    int* starts    = (int*)(ws + 131072);

    build_copy_kernel<<<STRIPEBLKS + COPYBLKS, 1024, 0, stream>>>(
        (const float2*)coords, (const float4*)values,
        sorted, starts, (float4*)out_values, out_coords);

    query_kernel<<<QBLOCKS, 256, 0, stream>>>(
        sorted, starts, (const float4*)values, spacing, shift,
        (float4*)out_values, out_coords);
}